// Round 6
// baseline (445.121 us; speedup 1.0000x reference)
//
#include <hip/hip_runtime.h>
#include <hip/hip_bf16.h>

// ---------------- types ----------------
typedef __attribute__((ext_vector_type(8))) short s16x8;   // 8 bf16 in 4 VGPRs
typedef __attribute__((ext_vector_type(4))) float f32x4;

// B=4, C=256, H=W=160, padded spatial 162, S dims 161, N=512, REID=128

__device__ __forceinline__ void async_ld16(const void* g, void* l) {
  __builtin_amdgcn_global_load_lds(
      (const __attribute__((address_space(1))) void*)g,
      (__attribute__((address_space(3))) void*)l, 16, 0, 0);
}

// ---------------- 0. zero only the pad borders of xpad and f1 ----------------
__global__ __launch_bounds__(256) void zero_borders(__hip_bfloat16* __restrict__ xpad,
                                                    __hip_bfloat16* __restrict__ f1) {
  int bi = blockIdx.x;
  int buf = bi / 2576; int rem = bi - buf * 2576;
  int b = rem / 644;   int e = rem - b * 644;
  int y, x;
  if (e < 162)      { y = 0;           x = e; }
  else if (e < 324) { y = 161;         x = e - 162; }
  else if (e < 484) { y = e - 324 + 1; x = 0; }
  else              { y = e - 484 + 1; x = 161; }
  __hip_bfloat16* p = (buf ? f1 : xpad) + (((size_t)b * 162 + y) * 162 + x) * 256 + threadIdx.x;
  *p = __float2bfloat16(0.f);
}

// ---------------- 1. NCHW fp32 -> padded NHWC bf16 ----------------
__global__ __launch_bounds__(256) void nchw2nhwc(const float* __restrict__ x,
                                                 __hip_bfloat16* __restrict__ xpad) {
  __shared__ float tile[32][33];
  int blk = blockIdx.x;
  int xt = blk % 5;
  int ct = (blk / 5) & 7;
  int by = blk / 40;
  int b = by / 160, y = by - (by / 160) * 160;
  int tx = threadIdx.x, ty = threadIdx.y;
  const float* src = x + (((size_t)(b * 256 + ct * 32)) * 160 + y) * 160 + xt * 32 + tx;
#pragma unroll
  for (int k = 0; k < 4; k++) tile[ty * 4 + k][tx] = src[(size_t)(ty * 4 + k) * 25600];
  __syncthreads();
  __hip_bfloat16* dst = xpad + (((size_t)(b * 162 + y + 1)) * 162 + (xt * 32 + 1)) * 256 + ct * 32 + tx;
#pragma unroll
  for (int k = 0; k < 4; k++) {
    int xx = ty * 4 + k;
    dst[(size_t)xx * 256] = __float2bfloat16(tile[tx][xx]);
  }
}

// ---------------- 2. weight pack: (L,Cout,Cin,3,3) fp32 -> [L][tap][co][ci] bf16 ----------------
__global__ __launch_bounds__(256) void pack_w(const float* __restrict__ cw,
                                              __hip_bfloat16* __restrict__ wpk) {
  int t = blockIdx.x * 256 + threadIdx.x;
  int ci = t & 255, co = (t >> 8) & 255, rest = t >> 16;
  int tap = rest % 9, l = rest / 9;
  int dy = tap / 3, dx = tap - dy * 3;
  float v = cw[((((size_t)l * 256 + co) * 256 + ci) * 3 + dy) * 3 + dx];
  wpk[(((size_t)l * 9 + tap) * 256 + co) * 256 + ci] = __float2bfloat16(v);
}

// ---------------- 3. fold conv-bias + BN into per-channel alpha/beta ----------------
__global__ void prep_bn(const float* __restrict__ cb, const float* __restrict__ g,
                        const float* __restrict__ bt, const float* __restrict__ mn,
                        const float* __restrict__ vr, float* __restrict__ ab) {
  int t = blockIdx.x * 256 + threadIdx.x;  // 512
  float a = g[t] / sqrtf(vr[t] + 1e-5f);
  ab[t] = a;
  ab[512 + t] = (cb[t] - mn[t]) * a + bt[t];
}

// ---------------- 3b. transpose MLP weights for coalesced reads ----------------
__global__ __launch_bounds__(256) void pack_mlp(const float* __restrict__ w1,
                                                const float* __restrict__ w2,
                                                float* __restrict__ w1t,
                                                float* __restrict__ w2t) {
  int t = blockIdx.x * 256 + threadIdx.x;
  if (t < 32768) {
    int h = t >> 8, k = t & 255;
    w1t[k * 128 + h] = w1[h * 256 + k];
  } else {
    int u = t - 32768;
    int r = u >> 7, k = u & 127;
    w2t[k * 128 + r] = w2[r * 128 + k];
  }
}

// ---------------- 4. conv3x3 + BN + ReLU, implicit GEMM (bf16 MFMA) ----------------
// BM=256, BN=256 (full N), BK=64; 512 threads / 8 waves (2M x 4N), wave-tile 128x64.
// Double-buffered LDS (128 KB, 1 block/CU); stage(u+1) issued BEFORE compute(u);
// per K-step each SIMD has ~2048 cy of MFMA to hide the staging latency.
// LDS linear, XOR-swizzled via pre-swizzled global source (rule #21); T1 XCD swizzle.
__global__ __launch_bounds__(512, 2) void conv_bn_relu(
    const __hip_bfloat16* __restrict__ inp, __hip_bfloat16* __restrict__ outp,
    const __hip_bfloat16* __restrict__ wpk,  // [9][256][256] (tap, co, ci)
    const float* __restrict__ alpha, const float* __restrict__ beff) {
  __shared__ __align__(16) short As[2 * 256 * 64];   // 64 KB
  __shared__ __align__(16) short Bs[2 * 256 * 64];   // 64 KB
  const int t = threadIdx.x;
  // T1: bijective XCD swizzle (grid 400 = 8*50)
  const int mtile = ((blockIdx.x & 7) * 50) + (blockIdx.x >> 3);  // 0..399
  const int l = t & 63;
  const int wv = t >> 6;                 // 0..7
  const int lr = l & 15, lq = l >> 4;
  const int wm = wv >> 2, wn = wv & 3;   // 2M x 4N; wave-tile rows wm*128.., cols wn*64..

  // staging: issue group covers 64 rows; thread t -> row (t>>3), 16B slot (t&7).
  // source pre-swizzle: logical slot = (t&7) ^ (row&7); LDS dest stays linear.
  const int srow = t >> 3;                              // 0..63
  const int koff = (((t & 7) ^ (srow & 7)) << 3);       // logical k-offset (shorts)
  const short* inS = (const short*)inp;
  const short* wS = (const short*)wpk;
  long abase[4];
#pragma unroll
  for (int i = 0; i < 4; i++) {
    int p = mtile * 256 + i * 64 + srow;
    int b = p / 25600; int r = p - b * 25600; int y = r / 160; int x = r - y * 160;
    abase[i] = (((long)b * 162 + y) * 162 + x) * 256 + koff;
  }
  const long bbase = ((long)srow) * 256 + koff;  // co = i*64 + srow -> + i*16384

  // stage K-step v (tap = v>>2, kc = v&3) into buffer v&1
  auto stage = [&](int v) {
    const int tap = v >> 2, kc = v & 3;
    const int dy = tap / 3, dx = tap - dy * 3;
    const long aoff = ((long)(dy * 162 + dx)) * 256 + kc * 64;
    const long boff = (long)tap * 65536 + kc * 64;
    short* ad = As + (v & 1) * 16384 + t * 8;
    short* bd = Bs + (v & 1) * 16384 + t * 8;
#pragma unroll
    for (int i = 0; i < 4; i++)
      async_ld16(inS + abase[i] + aoff, ad + i * 4096);
#pragma unroll
    for (int i = 0; i < 4; i++)
      async_ld16(wS + bbase + boff + (long)i * 16384, bd + i * 4096);
  };

  f32x4 acc[8][4];
#pragma unroll
  for (int i = 0; i < 8; i++)
#pragma unroll
    for (int j = 0; j < 4; j++) acc[i][j] = (f32x4){0.f, 0.f, 0.f, 0.f};

  stage(0);
  __syncthreads();  // buf0 ready

#pragma unroll 2
  for (int u = 0; u < 36; ++u) {
    if (u < 35) stage(u + 1);  // into buf (u+1)&1; in flight across this step's compute
    const short* Ab = As + (u & 1) * 16384;
    const short* Bb = Bs + (u & 1) * 16384;
#pragma unroll
    for (int kk = 0; kk < 2; ++kk) {
      const int ps = (((kk << 2) | lq) ^ (lr & 7)) << 3;  // swizzled slot (shorts)
      s16x8 av[8], bv[4];
#pragma unroll
      for (int mi = 0; mi < 8; ++mi)
        av[mi] = *(const s16x8*)&Ab[(wm * 128 + mi * 16 + lr) * 64 + ps];
#pragma unroll
      for (int ni = 0; ni < 4; ++ni)
        bv[ni] = *(const s16x8*)&Bb[(wn * 64 + ni * 16 + lr) * 64 + ps];
      __builtin_amdgcn_s_setprio(1);
#pragma unroll
      for (int mi = 0; mi < 8; ++mi)
#pragma unroll
        for (int ni = 0; ni < 4; ++ni)
          acc[mi][ni] = __builtin_amdgcn_mfma_f32_16x16x32_bf16(av[mi], bv[ni], acc[mi][ni], 0, 0, 0);
      __builtin_amdgcn_s_setprio(0);
    }
    __syncthreads();  // drains this step's prefetch (hidden under ~2048cy of MFMA)
  }

  // epilogue: y = relu(acc*alpha + beff) -> bf16, padded NHWC
  float al[4], be_[4];
#pragma unroll
  for (int ni = 0; ni < 4; ++ni) {
    int co = wn * 64 + ni * 16 + lr;
    al[ni] = alpha[co];
    be_[ni] = beff[co];
  }
#pragma unroll
  for (int mi = 0; mi < 8; ++mi) {
    int prow = mtile * 256 + wm * 128 + mi * 16 + lq * 4;
#pragma unroll
    for (int j = 0; j < 4; ++j) {
      int p = prow + j;
      int b = p / 25600; int r = p - b * 25600; int y = r / 160; int x = r - y * 160;
      long ob = (((long)b * 162 + (y + 1)) * 162 + (x + 1)) * 256 + wn * 64;
#pragma unroll
      for (int ni = 0; ni < 4; ++ni) {
        float v = acc[mi][ni][j] * al[ni] + be_[ni];
        outp[ob + ni * 16 + lr] = __float2bfloat16(fmaxf(v, 0.f));
      }
    }
  }
}

// ---------------- 5. cumsum along W: bf16 f -> fp32 S, channel-pair vectorized ----------------
__global__ __launch_bounds__(256) void cumsum_w(const __hip_bfloat16* __restrict__ f2,
                                                float* __restrict__ S) {
  int row = blockIdx.x * 2 + (threadIdx.x >> 7);   // 0..639
  int b = row / 160, y = row - (row / 160) * 160;
  int cp = threadIdx.x & 127;                      // channel pair index
  const unsigned* src =
      (const unsigned*)((const short*)f2 + (((size_t)b * 162 + y + 1) * 162 + 1) * 256) + cp;
  float2* dst = (float2*)(S + (((size_t)b * 161 + y + 1) * 161) * 256) + cp;
  dst[0] = float2{0.f, 0.f};
  float r0 = 0.f, r1 = 0.f;
  for (int x4 = 0; x4 < 160; x4 += 4) {
    unsigned v[4];
#pragma unroll
    for (int k = 0; k < 4; k++) v[k] = src[(size_t)(x4 + k) * 128];
#pragma unroll
    for (int k = 0; k < 4; k++) {
      r0 += __uint_as_float((v[k] & 0xffffu) << 16);
      r1 += __uint_as_float(v[k] & 0xffff0000u);
      dst[(size_t)(x4 + k + 1) * 128] = float2{r0, r1};
    }
  }
}

// ---------------- 6. cumsum along H in place ----------------
__global__ __launch_bounds__(256) void cumsum_h(float* __restrict__ S) {
  int bi = blockIdx.x;  // 4*161
  int b = bi / 161, q = bi - (bi / 161) * 161;
  int c = threadIdx.x;
  float* col = S + (((size_t)b * 161) * 161 + q) * 256 + c;
  const size_t ys = (size_t)161 * 256;
  col[0] = 0.f;
  float run = 0.f;
  for (int y0 = 1; y0 <= 160; y0 += 8) {
    float v[8];
#pragma unroll
    for (int k = 0; k < 8; k++) v[k] = col[(size_t)(y0 + k) * ys];
#pragma unroll
    for (int k = 0; k < 8; k++) { run += v[k]; col[(size_t)(y0 + k) * ys] = run; }
  }
}

// ---------------- 7. ROI adaptive 7x7 pool + global avg via integral image ----------------
__global__ __launch_bounds__(256) void roi_pool(const float* __restrict__ S,
                                                const float* __restrict__ bbox,
                                                float* __restrict__ pooled,
                                                int* __restrict__ valid) {
  int bn = blockIdx.x;  // 0..2047
  int b = bn >> 9;
  int c = threadIdx.x;
  float bx1 = bbox[bn * 4 + 0], by1 = bbox[bn * 4 + 1];
  float bx2 = bbox[bn * 4 + 2], by2 = bbox[bn * 4 + 3];
  int x1 = min(max((int)floorf(bx1 * 160.f), 0), 160);
  int y1 = min(max((int)floorf(by1 * 160.f), 0), 160);
  int x2 = min(max((int)floorf(bx2 * 160.f), 0), 160);
  int y2 = min(max((int)floorf(by2 * 160.f), 0), 160);
  int vld = (x2 > x1 && y2 > y1) ? 1 : 0;
  int hl = max(y2 - y1, 1), wl = max(x2 - x1, 1);
  int hs[7], he[7], ws_[7], we_[7];
  float rh[7], rw[7];
#pragma unroll
  for (int i = 0; i < 7; i++) {
    hs[i] = y1 + (i * hl) / 7;
    he[i] = y1 + ((i + 1) * hl + 6) / 7;
    rh[i] = 1.f / (float)(he[i] - hs[i]);
    ws_[i] = x1 + (i * wl) / 7;
    we_[i] = x1 + ((i + 1) * wl + 6) / 7;
    rw[i] = 1.f / (float)(we_[i] - ws_[i]);
  }
  const float* Sb = S + (size_t)b * 161 * 161 * 256 + c;
  float acc = 0.f;
#pragma unroll
  for (int i = 0; i < 7; i++) {
    const float* rE = Sb + (size_t)he[i] * (161 * 256);
    const float* rS = Sb + (size_t)hs[i] * (161 * 256);
#pragma unroll
    for (int j = 0; j < 7; j++) {
      size_t qe = (size_t)we_[j] * 256, qs = (size_t)ws_[j] * 256;
      float s = rE[qe] - rS[qe] - rE[qs] + rS[qs];
      acc += s * (rh[i] * rw[j]);
    }
  }
  pooled[(size_t)bn * 256 + c] = acc * (1.f / 49.f);
  if (c == 0) valid[bn] = vld;
}

// ---------------- 8. MLP (256->128 relu ->128) + mask + L2 normalize ----------------
__global__ __launch_bounds__(128) void mlp_norm(const float* __restrict__ pooled,
                                                const int* __restrict__ valid,
                                                const float* __restrict__ w1t,
                                                const float* __restrict__ b1,
                                                const float* __restrict__ w2t,
                                                const float* __restrict__ b2,
                                                float* __restrict__ out) {
  int bn = blockIdx.x;
  int t = threadIdx.x;
  __shared__ float pl[256];
  __shared__ float hh[128];
  __shared__ float red[2];
  pl[t] = pooled[(size_t)bn * 256 + t];
  pl[t + 128] = pooled[(size_t)bn * 256 + 128 + t];
  __syncthreads();
  float a = b1[t];
#pragma unroll 8
  for (int k = 0; k < 256; k++) a += w1t[k * 128 + t] * pl[k];
  hh[t] = fmaxf(a, 0.f);
  __syncthreads();
  float f = b2[t];
#pragma unroll 8
  for (int k = 0; k < 128; k++) f += w2t[k * 128 + t] * hh[k];
  if (!valid[bn]) f = 0.f;
  float ss = f * f;
#pragma unroll
  for (int off = 32; off > 0; off >>= 1) ss += __shfl_xor(ss, off);
  if ((t & 63) == 0) red[t >> 6] = ss;
  __syncthreads();
  float nrm = fmaxf(sqrtf(red[0] + red[1]), 1e-12f);
  out[(size_t)bn * 128 + t] = f / nrm;
}

// ---------------- launch ----------------
extern "C" void kernel_launch(void* const* d_in, const int* in_sizes, int n_in,
                              void* d_out, int out_size, void* d_ws, size_t ws_size,
                              hipStream_t stream) {
  const float* x = (const float*)d_in[0];
  const float* bboxes = (const float*)d_in[1];
  const float* conv_w = (const float*)d_in[2];
  const float* conv_b = (const float*)d_in[3];
  const float* bn_g = (const float*)d_in[4];
  const float* bn_b = (const float*)d_in[5];
  const float* bn_m = (const float*)d_in[6];
  const float* bn_v = (const float*)d_in[7];
  const float* w1 = (const float*)d_in[8];
  const float* b1 = (const float*)d_in[9];
  const float* w2 = (const float*)d_in[10];
  const float* b2 = (const float*)d_in[11];

  char* ws = (char*)d_ws;
  const size_t PADB = (size_t)4 * 162 * 162 * 256 * 2;   // 53,747,712 B
  const size_t WPKB = (size_t)2 * 9 * 256 * 256 * 2;     // 2,359,296 B
  const size_t SB = (size_t)4 * 161 * 161 * 256 * 4;     // 106,172,416 B
  const size_t PLB = (size_t)4 * 512 * 256 * 4;          // pooled 2 MB

  __hip_bfloat16* xpad = (__hip_bfloat16*)(ws);
  __hip_bfloat16* f1 = (__hip_bfloat16*)(ws + PADB);
  __hip_bfloat16* wpk = (__hip_bfloat16*)(ws + 2 * PADB);
  float* abuf = (float*)(ws + 2 * PADB + WPKB);
  float* S = (float*)(ws + 2 * PADB + WPKB + 4096);
  float* pooled = (float*)(ws + 2 * PADB + WPKB + 4096 + SB);
  int* valid = (int*)(ws + 2 * PADB + WPKB + 4096 + SB + PLB);
  float* w1t = (float*)(ws + 2 * PADB + WPKB + 4096 + SB + PLB + 8192);
  float* w2t = w1t + 32768;

  zero_borders<<<5152, 256, 0, stream>>>(xpad, f1);
  nchw2nhwc<<<25600, dim3(32, 8), 0, stream>>>(x, xpad);
  pack_w<<<4608, 256, 0, stream>>>(conv_w, wpk);
  prep_bn<<<2, 256, 0, stream>>>(conv_b, bn_g, bn_b, bn_m, bn_v, abuf);
  pack_mlp<<<192, 256, 0, stream>>>(w1, w2, w1t, w2t);

  conv_bn_relu<<<400, 512, 0, stream>>>(xpad, f1, wpk, abuf, abuf + 512);
  conv_bn_relu<<<400, 512, 0, stream>>>(f1, xpad, wpk + (size_t)9 * 256 * 256, abuf + 256, abuf + 768);

  cumsum_w<<<320, 256, 0, stream>>>(xpad, S);
  cumsum_h<<<644, 256, 0, stream>>>(S);
  roi_pool<<<2048, 256, 0, stream>>>(S, bboxes, pooled, valid);
  mlp_norm<<<2048, 128, 0, stream>>>(pooled, valid, w1t, b1, w2t, b2, (float*)d_out);
}

// Round 7
// 429.336 us; speedup vs baseline: 1.0368x; 1.0368x over previous
//
#include <hip/hip_runtime.h>
#include <hip/hip_bf16.h>

// ---------------- types ----------------
typedef __attribute__((ext_vector_type(8))) short s16x8;   // 8 bf16 in 4 VGPRs
typedef __attribute__((ext_vector_type(4))) float f32x4;

// B=4, C=256, H=W=160, padded spatial 162, S dims 161, N=512, REID=128

__device__ __forceinline__ void async_ld16(const void* g, void* l) {
  __builtin_amdgcn_global_load_lds(
      (const __attribute__((address_space(1))) void*)g,
      (__attribute__((address_space(3))) void*)l, 16, 0, 0);
}

#define CFENCE asm volatile("" ::: "memory")
#define BARRIER do { CFENCE; __builtin_amdgcn_s_barrier(); CFENCE; } while (0)

// ---------------- 0. zero only the pad borders of xpad and f1 ----------------
__global__ __launch_bounds__(256) void zero_borders(__hip_bfloat16* __restrict__ xpad,
                                                    __hip_bfloat16* __restrict__ f1) {
  int bi = blockIdx.x;
  int buf = bi / 2576; int rem = bi - buf * 2576;
  int b = rem / 644;   int e = rem - b * 644;
  int y, x;
  if (e < 162)      { y = 0;           x = e; }
  else if (e < 324) { y = 161;         x = e - 162; }
  else if (e < 484) { y = e - 324 + 1; x = 0; }
  else              { y = e - 484 + 1; x = 161; }
  __hip_bfloat16* p = (buf ? f1 : xpad) + (((size_t)b * 162 + y) * 162 + x) * 256 + threadIdx.x;
  *p = __float2bfloat16(0.f);
}

// ---------------- 1. NCHW fp32 -> padded NHWC bf16 ----------------
__global__ __launch_bounds__(256) void nchw2nhwc(const float* __restrict__ x,
                                                 __hip_bfloat16* __restrict__ xpad) {
  __shared__ float tile[32][33];
  int blk = blockIdx.x;
  int xt = blk % 5;
  int ct = (blk / 5) & 7;
  int by = blk / 40;
  int b = by / 160, y = by - (by / 160) * 160;
  int tx = threadIdx.x, ty = threadIdx.y;
  const float* src = x + (((size_t)(b * 256 + ct * 32)) * 160 + y) * 160 + xt * 32 + tx;
#pragma unroll
  for (int k = 0; k < 4; k++) tile[ty * 4 + k][tx] = src[(size_t)(ty * 4 + k) * 25600];
  __syncthreads();
  __hip_bfloat16* dst = xpad + (((size_t)(b * 162 + y + 1)) * 162 + (xt * 32 + 1)) * 256 + ct * 32 + tx;
#pragma unroll
  for (int k = 0; k < 4; k++) {
    int xx = ty * 4 + k;
    dst[(size_t)xx * 256] = __float2bfloat16(tile[tx][xx]);
  }
}

// ---------------- 2. weight pack: (L,Cout,Cin,3,3) fp32 -> [L][tap][co][ci] bf16 ----------------
__global__ __launch_bounds__(256) void pack_w(const float* __restrict__ cw,
                                              __hip_bfloat16* __restrict__ wpk) {
  int t = blockIdx.x * 256 + threadIdx.x;
  int ci = t & 255, co = (t >> 8) & 255, rest = t >> 16;
  int tap = rest % 9, l = rest / 9;
  int dy = tap / 3, dx = tap - dy * 3;
  float v = cw[((((size_t)l * 256 + co) * 256 + ci) * 3 + dy) * 3 + dx];
  wpk[(((size_t)l * 9 + tap) * 256 + co) * 256 + ci] = __float2bfloat16(v);
}

// ---------------- 3. fold conv-bias + BN into per-channel alpha/beta ----------------
__global__ void prep_bn(const float* __restrict__ cb, const float* __restrict__ g,
                        const float* __restrict__ bt, const float* __restrict__ mn,
                        const float* __restrict__ vr, float* __restrict__ ab) {
  int t = blockIdx.x * 256 + threadIdx.x;  // 512
  float a = g[t] / sqrtf(vr[t] + 1e-5f);
  ab[t] = a;
  ab[512 + t] = (cb[t] - mn[t]) * a + bt[t];
}

// ---------------- 3b. transpose MLP weights for coalesced reads ----------------
__global__ __launch_bounds__(256) void pack_mlp(const float* __restrict__ w1,
                                                const float* __restrict__ w2,
                                                float* __restrict__ w1t,
                                                float* __restrict__ w2t) {
  int t = blockIdx.x * 256 + threadIdx.x;
  if (t < 32768) {
    int h = t >> 8, k = t & 255;
    w1t[k * 128 + h] = w1[h * 256 + k];
  } else {
    int u = t - 32768;
    int r = u >> 7, k = u & 127;
    w2t[k * 128 + r] = w2[r * 128 + k];
  }
}

// ---------------- 4. conv3x3 + BN + ReLU: implicit GEMM, m201-style 8-phase schedule ----------
// BM=256, BN=256 (full N), BK=64; 512 thr / 8 waves (2M x 4N), wave-tile 128x64, acc 8x4.
// Per K-tile: 4 phases {ds_read frags | stage 1 half-tile | bar | 16 MFMA | bar}.
// Counted s_waitcnt vmcnt(2) once per K-tile (phase 3) -- never drain 0 in steady state.
// Half-tile stage order B1,A0,A1,B0(t+2): every LDS write >=2 barriers after last reader.
// LDS linear dest + pre-swizzled source + swizzled read (rule #21, involution slot^=row&7).
__global__ __launch_bounds__(512, 2) void conv_bn_relu(
    const __hip_bfloat16* __restrict__ inp, __hip_bfloat16* __restrict__ outp,
    const __hip_bfloat16* __restrict__ wpk,  // [9][256][256] (tap, co, ci)
    const float* __restrict__ alpha, const float* __restrict__ beff) {
  __shared__ __align__(16) short As[2 * 256 * 64];   // 64 KB (2 dbuf x 256 rows x 64 k)
  __shared__ __align__(16) short Bs[2 * 256 * 64];   // 64 KB
  const int t = threadIdx.x;
  // T1: bijective XCD swizzle (grid 400 = 8*50)
  const int mtile = ((blockIdx.x & 7) * 50) + (blockIdx.x >> 3);  // 0..399
  const int l = t & 63;
  const int wv = t >> 6;                 // 0..7
  const int lr = l & 15, lq = l >> 4;
  const int wm = wv >> 2, wn = wv & 3;   // 2M x 4N; wave rows wm*128.., cols wn*64..

  // staging geometry: half-tile = 128 rows x 64 k = 16 KB = 2 issues x 512 thr x 16B.
  // thread t -> row j*64 + (t>>3), phys 16B slot (t&7); source slot pre-swizzled ^(row&7).
  const int srow = t >> 3;                              // 0..63
  const int koff = (((t & 7) ^ (srow & 7)) << 3);       // logical k-offset (shorts)
  const short* inS = (const short*)inp;
  const short* wS = (const short*)wpk;
  long abase[4];
#pragma unroll
  for (int i = 0; i < 4; i++) {
    int p = mtile * 256 + i * 64 + srow;
    int b = p / 25600; int r = p - b * 25600; int y = r / 160; int x = r - y * 160;
    abase[i] = (((long)b * 162 + y) * 162 + x) * 256 + koff;
  }
  const long bbase = ((long)srow) * 256 + koff;

  // stage half h (rows h*128..h*128+127) of K-tile v into dbuf v&1
  auto stageA = [&](int v, int h) {
    const int tap = v >> 2, kc = v & 3;
    const int dy = tap / 3, dx = tap - dy * 3;
    const long aoff = ((long)(dy * 162 + dx)) * 256 + kc * 64;
    short* d = As + (v & 1) * 16384 + h * 8192 + t * 8;
    async_ld16(inS + abase[h * 2 + 0] + aoff, d);
    async_ld16(inS + abase[h * 2 + 1] + aoff, d + 4096);
  };
  auto stageB = [&](int v, int h) {
    const int tap = v >> 2, kc = v & 3;
    const long boff = (long)tap * 65536 + kc * 64;
    short* d = Bs + (v & 1) * 16384 + h * 8192 + t * 8;
    async_ld16(wS + bbase + (long)(h * 2 + 0) * 16384 + boff, d);
    async_ld16(wS + bbase + (long)(h * 2 + 1) * 16384 + boff, d + 4096);
  };

  f32x4 acc[8][4];
#pragma unroll
  for (int i = 0; i < 8; i++)
#pragma unroll
    for (int j = 0; j < 4; j++) acc[i][j] = (f32x4){0.f, 0.f, 0.f, 0.f};

  // fragment readers (swizzled slot; (row&7)==lr&7 for all frags)
  auto rdA = [&](const short* Ab, int mi, int kk) {
    return *(const s16x8*)&Ab[(wm * 128 + mi * 16 + lr) * 64 +
                              ((((kk << 2) | lq) ^ (lr & 7)) << 3)];
  };
  auto rdB = [&](const short* Bb, int ni, int kk) {
    return *(const s16x8*)&Bb[(wn * 64 + ni * 16 + lr) * 64 +
                              ((((kk << 2) | lq) ^ (lr & 7)) << 3)];
  };

  // prologue: tile0 fully + B0 of tile1; counted drain leaves B0(1) in flight
  stageB(0, 0); stageB(0, 1); stageA(0, 0); stageA(0, 1); stageB(1, 0);
  asm volatile("s_waitcnt vmcnt(2)" ::: "memory");
  BARRIER;

  s16x8 avlo[4], avhi[4], bv[4];
#pragma unroll 1
  for (int u = 0; u < 36; ++u) {
    const short* Ab = As + (u & 1) * 16384;
    const short* Bb = Bs + (u & 1) * 16384;
    // ---- phase 0: frags (kk0: avlo + bv), stage B1(u+1), MFMA mi0-3 ----
#pragma unroll
    for (int mi = 0; mi < 4; ++mi) avlo[mi] = rdA(Ab, mi, 0);
#pragma unroll
    for (int ni = 0; ni < 4; ++ni) bv[ni] = rdB(Bb, ni, 0);
    if (u + 1 < 36) stageB(u + 1, 1);
    BARRIER;
    __builtin_amdgcn_s_setprio(1);
#pragma unroll
    for (int mi = 0; mi < 4; ++mi)
#pragma unroll
      for (int ni = 0; ni < 4; ++ni)
        acc[mi][ni] = __builtin_amdgcn_mfma_f32_16x16x32_bf16(avlo[mi], bv[ni], acc[mi][ni], 0, 0, 0);
    __builtin_amdgcn_s_setprio(0);
    BARRIER;
    // ---- phase 1: frags (kk0: avhi), stage A0(u+1), MFMA mi4-7 (bv reused) ----
#pragma unroll
    for (int mi = 0; mi < 4; ++mi) avhi[mi] = rdA(Ab, mi + 4, 0);
    if (u + 1 < 36) stageA(u + 1, 0);
    BARRIER;
    __builtin_amdgcn_s_setprio(1);
#pragma unroll
    for (int mi = 0; mi < 4; ++mi)
#pragma unroll
      for (int ni = 0; ni < 4; ++ni)
        acc[mi + 4][ni] = __builtin_amdgcn_mfma_f32_16x16x32_bf16(avhi[mi], bv[ni], acc[mi + 4][ni], 0, 0, 0);
    __builtin_amdgcn_s_setprio(0);
    BARRIER;
    // ---- phase 2: frags (kk1: avlo + bv), stage A1(u+1), MFMA mi0-3 ----
#pragma unroll
    for (int mi = 0; mi < 4; ++mi) avlo[mi] = rdA(Ab, mi, 1);
#pragma unroll
    for (int ni = 0; ni < 4; ++ni) bv[ni] = rdB(Bb, ni, 1);
    if (u + 1 < 36) stageA(u + 1, 1);
    BARRIER;
    __builtin_amdgcn_s_setprio(1);
#pragma unroll
    for (int mi = 0; mi < 4; ++mi)
#pragma unroll
      for (int ni = 0; ni < 4; ++ni)
        acc[mi][ni] = __builtin_amdgcn_mfma_f32_16x16x32_bf16(avlo[mi], bv[ni], acc[mi][ni], 0, 0, 0);
    __builtin_amdgcn_s_setprio(0);
    BARRIER;
    // ---- phase 3: frags (kk1: avhi), stage B0(u+2), counted vmcnt, MFMA mi4-7 ----
#pragma unroll
    for (int mi = 0; mi < 4; ++mi) avhi[mi] = rdA(Ab, mi + 4, 1);
    if (u + 2 < 36) {
      stageB(u + 2, 0);
      asm volatile("s_waitcnt vmcnt(2)" ::: "memory");  // all of tile u+1 landed
    } else if (u + 1 < 36) {
      asm volatile("s_waitcnt vmcnt(0)" ::: "memory");  // peel: drain tile 35
    }
    BARRIER;
    __builtin_amdgcn_s_setprio(1);
#pragma unroll
    for (int mi = 0; mi < 4; ++mi)
#pragma unroll
      for (int ni = 0; ni < 4; ++ni)
        acc[mi + 4][ni] = __builtin_amdgcn_mfma_f32_16x16x32_bf16(avhi[mi], bv[ni], acc[mi + 4][ni], 0, 0, 0);
    __builtin_amdgcn_s_setprio(0);
    BARRIER;
  }

  // epilogue: y = relu(acc*alpha + beff) -> bf16, padded NHWC
  float al[4], be_[4];
#pragma unroll
  for (int ni = 0; ni < 4; ++ni) {
    int co = wn * 64 + ni * 16 + lr;
    al[ni] = alpha[co];
    be_[ni] = beff[co];
  }
#pragma unroll
  for (int mi = 0; mi < 8; ++mi) {
    int prow = mtile * 256 + wm * 128 + mi * 16 + lq * 4;
#pragma unroll
    for (int j = 0; j < 4; ++j) {
      int p = prow + j;
      int b = p / 25600; int r = p - b * 25600; int y = r / 160; int x = r - y * 160;
      long ob = (((long)b * 162 + (y + 1)) * 162 + (x + 1)) * 256 + wn * 64;
#pragma unroll
      for (int ni = 0; ni < 4; ++ni) {
        float v = acc[mi][ni][j] * al[ni] + be_[ni];
        outp[ob + ni * 16 + lr] = __float2bfloat16(fmaxf(v, 0.f));
      }
    }
  }
}

// ---------------- 5. cumsum along W: bf16 f -> fp32 S, channel-pair vectorized ----------------
__global__ __launch_bounds__(256) void cumsum_w(const __hip_bfloat16* __restrict__ f2,
                                                float* __restrict__ S) {
  int row = blockIdx.x * 2 + (threadIdx.x >> 7);   // 0..639
  int b = row / 160, y = row - (row / 160) * 160;
  int cp = threadIdx.x & 127;                      // channel pair index
  const unsigned* src =
      (const unsigned*)((const short*)f2 + (((size_t)b * 162 + y + 1) * 162 + 1) * 256) + cp;
  float2* dst = (float2*)(S + (((size_t)b * 161 + y + 1) * 161) * 256) + cp;
  dst[0] = float2{0.f, 0.f};
  float r0 = 0.f, r1 = 0.f;
  for (int x4 = 0; x4 < 160; x4 += 4) {
    unsigned v[4];
#pragma unroll
    for (int k = 0; k < 4; k++) v[k] = src[(size_t)(x4 + k) * 128];
#pragma unroll
    for (int k = 0; k < 4; k++) {
      r0 += __uint_as_float((v[k] & 0xffffu) << 16);
      r1 += __uint_as_float(v[k] & 0xffff0000u);
      dst[(size_t)(x4 + k + 1) * 128] = float2{r0, r1};
    }
  }
}

// ---------------- 6. cumsum along H in place ----------------
__global__ __launch_bounds__(256) void cumsum_h(float* __restrict__ S) {
  int bi = blockIdx.x;  // 4*161
  int b = bi / 161, q = bi - (bi / 161) * 161;
  int c = threadIdx.x;
  float* col = S + (((size_t)b * 161) * 161 + q) * 256 + c;
  const size_t ys = (size_t)161 * 256;
  col[0] = 0.f;
  float run = 0.f;
  for (int y0 = 1; y0 <= 160; y0 += 8) {
    float v[8];
#pragma unroll
    for (int k = 0; k < 8; k++) v[k] = col[(size_t)(y0 + k) * ys];
#pragma unroll
    for (int k = 0; k < 8; k++) { run += v[k]; col[(size_t)(y0 + k) * ys] = run; }
  }
}

// ---------------- 7. ROI adaptive 7x7 pool + global avg via integral image ----------------
__global__ __launch_bounds__(256) void roi_pool(const float* __restrict__ S,
                                                const float* __restrict__ bbox,
                                                float* __restrict__ pooled,
                                                int* __restrict__ valid) {
  int bn = blockIdx.x;  // 0..2047
  int b = bn >> 9;
  int c = threadIdx.x;
  float bx1 = bbox[bn * 4 + 0], by1 = bbox[bn * 4 + 1];
  float bx2 = bbox[bn * 4 + 2], by2 = bbox[bn * 4 + 3];
  int x1 = min(max((int)floorf(bx1 * 160.f), 0), 160);
  int y1 = min(max((int)floorf(by1 * 160.f), 0), 160);
  int x2 = min(max((int)floorf(bx2 * 160.f), 0), 160);
  int y2 = min(max((int)floorf(by2 * 160.f), 0), 160);
  int vld = (x2 > x1 && y2 > y1) ? 1 : 0;
  int hl = max(y2 - y1, 1), wl = max(x2 - x1, 1);
  int hs[7], he[7], ws_[7], we_[7];
  float rh[7], rw[7];
#pragma unroll
  for (int i = 0; i < 7; i++) {
    hs[i] = y1 + (i * hl) / 7;
    he[i] = y1 + ((i + 1) * hl + 6) / 7;
    rh[i] = 1.f / (float)(he[i] - hs[i]);
    ws_[i] = x1 + (i * wl) / 7;
    we_[i] = x1 + ((i + 1) * wl + 6) / 7;
    rw[i] = 1.f / (float)(we_[i] - ws_[i]);
  }
  const float* Sb = S + (size_t)b * 161 * 161 * 256 + c;
  float acc = 0.f;
#pragma unroll
  for (int i = 0; i < 7; i++) {
    const float* rE = Sb + (size_t)he[i] * (161 * 256);
    const float* rS = Sb + (size_t)hs[i] * (161 * 256);
#pragma unroll
    for (int j = 0; j < 7; j++) {
      size_t qe = (size_t)we_[j] * 256, qs = (size_t)ws_[j] * 256;
      float s = rE[qe] - rS[qe] - rE[qs] + rS[qs];
      acc += s * (rh[i] * rw[j]);
    }
  }
  pooled[(size_t)bn * 256 + c] = acc * (1.f / 49.f);
  if (c == 0) valid[bn] = vld;
}

// ---------------- 8. MLP (256->128 relu ->128) + mask + L2 normalize ----------------
__global__ __launch_bounds__(128) void mlp_norm(const float* __restrict__ pooled,
                                                const int* __restrict__ valid,
                                                const float* __restrict__ w1t,
                                                const float* __restrict__ b1,
                                                const float* __restrict__ w2t,
                                                const float* __restrict__ b2,
                                                float* __restrict__ out) {
  int bn = blockIdx.x;
  int t = threadIdx.x;
  __shared__ float pl[256];
  __shared__ float hh[128];
  __shared__ float red[2];
  pl[t] = pooled[(size_t)bn * 256 + t];
  pl[t + 128] = pooled[(size_t)bn * 256 + 128 + t];
  __syncthreads();
  float a = b1[t];
#pragma unroll 8
  for (int k = 0; k < 256; k++) a += w1t[k * 128 + t] * pl[k];
  hh[t] = fmaxf(a, 0.f);
  __syncthreads();
  float f = b2[t];
#pragma unroll 8
  for (int k = 0; k < 128; k++) f += w2t[k * 128 + t] * hh[k];
  if (!valid[bn]) f = 0.f;
  float ss = f * f;
#pragma unroll
  for (int off = 32; off > 0; off >>= 1) ss += __shfl_xor(ss, off);
  if ((t & 63) == 0) red[t >> 6] = ss;
  __syncthreads();
  float nrm = fmaxf(sqrtf(red[0] + red[1]), 1e-12f);
  out[(size_t)bn * 128 + t] = f / nrm;
}

// ---------------- launch ----------------
extern "C" void kernel_launch(void* const* d_in, const int* in_sizes, int n_in,
                              void* d_out, int out_size, void* d_ws, size_t ws_size,
                              hipStream_t stream) {
  const float* x = (const float*)d_in[0];
  const float* bboxes = (const float*)d_in[1];
  const float* conv_w = (const float*)d_in[2];
  const float* conv_b = (const float*)d_in[3];
  const float* bn_g = (const float*)d_in[4];
  const float* bn_b = (const float*)d_in[5];
  const float* bn_m = (const float*)d_in[6];
  const float* bn_v = (const float*)d_in[7];
  const float* w1 = (const float*)d_in[8];
  const float* b1 = (const float*)d_in[9];
  const float* w2 = (const float*)d_in[10];
  const float* b2 = (const float*)d_in[11];

  char* ws = (char*)d_ws;
  const size_t PADB = (size_t)4 * 162 * 162 * 256 * 2;   // 53,747,712 B
  const size_t WPKB = (size_t)2 * 9 * 256 * 256 * 2;     // 2,359,296 B
  const size_t SB = (size_t)4 * 161 * 161 * 256 * 4;     // 106,172,416 B
  const size_t PLB = (size_t)4 * 512 * 256 * 4;          // pooled 2 MB

  __hip_bfloat16* xpad = (__hip_bfloat16*)(ws);
  __hip_bfloat16* f1 = (__hip_bfloat16*)(ws + PADB);
  __hip_bfloat16* wpk = (__hip_bfloat16*)(ws + 2 * PADB);
  float* abuf = (float*)(ws + 2 * PADB + WPKB);
  float* S = (float*)(ws + 2 * PADB + WPKB + 4096);
  float* pooled = (float*)(ws + 2 * PADB + WPKB + 4096 + SB);
  int* valid = (int*)(ws + 2 * PADB + WPKB + 4096 + SB + PLB);
  float* w1t = (float*)(ws + 2 * PADB + WPKB + 4096 + SB + PLB + 8192);
  float* w2t = w1t + 32768;

  zero_borders<<<5152, 256, 0, stream>>>(xpad, f1);
  nchw2nhwc<<<25600, dim3(32, 8), 0, stream>>>(x, xpad);
  pack_w<<<4608, 256, 0, stream>>>(conv_w, wpk);
  prep_bn<<<2, 256, 0, stream>>>(conv_b, bn_g, bn_b, bn_m, bn_v, abuf);
  pack_mlp<<<192, 256, 0, stream>>>(w1, w2, w1t, w2t);

  conv_bn_relu<<<400, 512, 0, stream>>>(xpad, f1, wpk, abuf, abuf + 512);
  conv_bn_relu<<<400, 512, 0, stream>>>(f1, xpad, wpk + (size_t)9 * 256 * 256, abuf + 256, abuf + 768);

  cumsum_w<<<320, 256, 0, stream>>>(xpad, S);
  cumsum_h<<<644, 256, 0, stream>>>(S);
  roi_pool<<<2048, 256, 0, stream>>>(S, bboxes, pooled, valid);
  mlp_norm<<<2048, 128, 0, stream>>>(pooled, valid, w1t, b1, w2t, b2, (float*)d_out);
}

// Round 8
// 407.535 us; speedup vs baseline: 1.0922x; 1.0535x over previous
//
#include <hip/hip_runtime.h>
#include <hip/hip_bf16.h>

// ---------------- types ----------------
typedef __attribute__((ext_vector_type(8))) short s16x8;   // 8 bf16 in 4 VGPRs
typedef __attribute__((ext_vector_type(4))) float f32x4;

// B=4, C=256, H=W=160, padded spatial 162, S dims 161, N=512, REID=128

__device__ __forceinline__ void async_ld16(const void* g, void* l) {
  __builtin_amdgcn_global_load_lds(
      (const __attribute__((address_space(1))) void*)g,
      (__attribute__((address_space(3))) void*)l, 16, 0, 0);
}

// ---------------- 0. merged prep: borders + weight pack + bn fold + mlp transpose ----------------
// blocks [0,5152): zero borders; [5152,9760): pack_w; [9760,9762): prep_bn; [9762,9954): pack_mlp
__global__ __launch_bounds__(256) void prep_all(
    __hip_bfloat16* __restrict__ xpad, __hip_bfloat16* __restrict__ f1,
    const float* __restrict__ cw, __hip_bfloat16* __restrict__ wpk,
    const float* __restrict__ cb, const float* __restrict__ g,
    const float* __restrict__ bt, const float* __restrict__ mn,
    const float* __restrict__ vr, float* __restrict__ ab,
    const float* __restrict__ w1, const float* __restrict__ w2,
    float* __restrict__ w1t, float* __restrict__ w2t) {
  int bi = blockIdx.x;
  if (bi < 5152) {
    int buf = bi / 2576; int rem = bi - buf * 2576;
    int b = rem / 644;   int e = rem - b * 644;
    int y, x;
    if (e < 162)      { y = 0;           x = e; }
    else if (e < 324) { y = 161;         x = e - 162; }
    else if (e < 484) { y = e - 324 + 1; x = 0; }
    else              { y = e - 484 + 1; x = 161; }
    __hip_bfloat16* p = (buf ? f1 : xpad) + (((size_t)b * 162 + y) * 162 + x) * 256 + threadIdx.x;
    *p = __float2bfloat16(0.f);
  } else if (bi < 9760) {
    int t = (bi - 5152) * 256 + threadIdx.x;
    int ci = t & 255, co = (t >> 8) & 255, rest = t >> 16;
    int tap = rest % 9, l = rest / 9;
    int dy = tap / 3, dx = tap - dy * 3;
    float v = cw[((((size_t)l * 256 + co) * 256 + ci) * 3 + dy) * 3 + dx];
    wpk[(((size_t)l * 9 + tap) * 256 + co) * 256 + ci] = __float2bfloat16(v);
  } else if (bi < 9762) {
    int t = (bi - 9760) * 256 + threadIdx.x;  // 512
    float a = g[t] / sqrtf(vr[t] + 1e-5f);
    ab[t] = a;
    ab[512 + t] = (cb[t] - mn[t]) * a + bt[t];
  } else {
    int t = (bi - 9762) * 256 + threadIdx.x;
    if (t < 32768) {
      int h = t >> 8, k = t & 255;
      w1t[k * 128 + h] = w1[h * 256 + k];
    } else {
      int u = t - 32768;
      int r = u >> 7, k = u & 127;
      w2t[k * 128 + r] = w2[r * 128 + k];
    }
  }
}

// ---------------- 1. NCHW fp32 -> padded NHWC bf16 (2 rows per block) ----------------
// grid 12800 = 5(xt) * 8(ct) * (4*80)(b, ypair); block (32,8)
__global__ __launch_bounds__(256) void nchw2nhwc(const float* __restrict__ x,
                                                 __hip_bfloat16* __restrict__ xpad) {
  __shared__ float tile[32][33];
  int blk = blockIdx.x;
  int xt = blk % 5;
  int ct = (blk / 5) & 7;
  int by = blk / 40;
  int b = by / 80, yp = by - (by / 80) * 80;
  int tx = threadIdx.x, ty = threadIdx.y;
#pragma unroll
  for (int ry = 0; ry < 2; ++ry) {
    int y = yp * 2 + ry;
    const float* src = x + (((size_t)(b * 256 + ct * 32)) * 160 + y) * 160 + xt * 32 + tx;
#pragma unroll
    for (int k = 0; k < 4; k++) tile[ty * 4 + k][tx] = src[(size_t)(ty * 4 + k) * 25600];
    __syncthreads();
    __hip_bfloat16* dst = xpad + (((size_t)(b * 162 + y + 1)) * 162 + (xt * 32 + 1)) * 256 + ct * 32 + tx;
#pragma unroll
    for (int k = 0; k < 4; k++) {
      int xx = ty * 4 + k;
      dst[(size_t)xx * 256] = __float2bfloat16(tile[tx][xx]);
    }
    __syncthreads();
  }
}

// ---------------- 4. conv3x3 + BN + ReLU, implicit GEMM (bf16 MFMA) — R5-proven structure -------
// BM=128, BN=256 (full N), BK=64; 4 waves, wave-tile 64x128 (4x8 frags of 16x16x32).
// 2-barrier K-step; LDS linear, XOR-swizzled via pre-swizzled global source; T1 XCD swizzle.
__global__ __launch_bounds__(256, 2) void conv_bn_relu(
    const __hip_bfloat16* __restrict__ inp, __hip_bfloat16* __restrict__ outp,
    const __hip_bfloat16* __restrict__ wpk,  // [9][256][256] (tap, co, ci)
    const float* __restrict__ alpha, const float* __restrict__ beff) {
  __shared__ __align__(16) short As[128 * 64];   // 16 KB
  __shared__ __align__(16) short Bs[256 * 64];   // 32 KB
  const int t = threadIdx.x;
  // T1: bijective XCD swizzle (grid 800 = 8*100)
  const int mtile = ((blockIdx.x & 7) * 100) + (blockIdx.x >> 3);  // 0..799
  const int l = t & 63;
  const int wv = t >> 6;
  const int lr = l & 15, lq = l >> 4;
  const int wm = wv >> 1, wn = wv & 1;  // wave-tile: rows wm*64.., cols wn*128..

  // staging: issue group covers 32 rows; thread t -> row (t>>3), 16B slot (t&7).
  // source pre-swizzle: logical slot = (t&7) ^ (row&7), LDS dest stays linear.
  const int srow = t >> 3;                              // 0..31
  const int koff = (((t & 7) ^ (srow & 7)) << 3);       // logical k-offset (shorts)
  const short* inS = (const short*)inp;
  const short* wS = (const short*)wpk;
  long abase[4];
#pragma unroll
  for (int i = 0; i < 4; i++) {
    int p = mtile * 128 + i * 32 + srow;
    int b = p / 25600; int r = p - b * 25600; int y = r / 160; int x = r - y * 160;
    abase[i] = (((long)b * 162 + y) * 162 + x) * 256 + koff;
  }
  const long bbase = ((long)srow) * 256 + koff;  // + j*8192 for row group j

  f32x4 acc[4][8];
#pragma unroll
  for (int i = 0; i < 4; i++)
#pragma unroll
    for (int j = 0; j < 8; j++) acc[i][j] = (f32x4){0.f, 0.f, 0.f, 0.f};

#pragma unroll 1
  for (int u = 0; u < 36; ++u) {
    const int tap = u >> 2, kc = u & 3;
    const int dy = tap / 3, dx = tap - dy * 3;
    const long aoff = ((long)(dy * 162 + dx)) * 256 + kc * 64;
    const long boff = (long)tap * 65536 + kc * 64;
    __syncthreads();  // previous step's LDS reads done
#pragma unroll
    for (int i = 0; i < 4; i++)
      async_ld16(inS + abase[i] + aoff, As + i * 2048 + t * 8);
#pragma unroll
    for (int j = 0; j < 8; j++)
      async_ld16(wS + bbase + boff + (long)j * 8192, Bs + j * 2048 + t * 8);
    __syncthreads();  // drains vmcnt(0): tiles ready
#pragma unroll
    for (int kk = 0; kk < 2; ++kk) {
      const int ps = (((kk << 2) | lq) ^ (lr & 7)) << 3;  // swizzled slot (shorts)
      s16x8 av[4], bv[8];
#pragma unroll
      for (int mi = 0; mi < 4; ++mi)
        av[mi] = *(const s16x8*)&As[(wm * 64 + mi * 16 + lr) * 64 + ps];
#pragma unroll
      for (int ni = 0; ni < 8; ++ni)
        bv[ni] = *(const s16x8*)&Bs[(wn * 128 + ni * 16 + lr) * 64 + ps];
#pragma unroll
      for (int mi = 0; mi < 4; ++mi)
#pragma unroll
        for (int ni = 0; ni < 8; ++ni)
          acc[mi][ni] = __builtin_amdgcn_mfma_f32_16x16x32_bf16(av[mi], bv[ni], acc[mi][ni], 0, 0, 0);
    }
  }

  // epilogue: y = relu(acc*alpha + beff) -> bf16, padded NHWC
  float al[8], be_[8];
#pragma unroll
  for (int ni = 0; ni < 8; ++ni) {
    int co = wn * 128 + ni * 16 + lr;
    al[ni] = alpha[co];
    be_[ni] = beff[co];
  }
#pragma unroll
  for (int mi = 0; mi < 4; ++mi) {
    int prow = mtile * 128 + wm * 64 + mi * 16 + lq * 4;
#pragma unroll
    for (int j = 0; j < 4; ++j) {
      int p = prow + j;
      int b = p / 25600; int r = p - b * 25600; int y = r / 160; int x = r - y * 160;
      long ob = (((long)b * 162 + (y + 1)) * 162 + (x + 1)) * 256 + wn * 128;
#pragma unroll
      for (int ni = 0; ni < 8; ++ni) {
        float v = acc[mi][ni][j] * al[ni] + be_[ni];
        outp[ob + ni * 16 + lr] = __float2bfloat16(fmaxf(v, 0.f));
      }
    }
  }
}

// ---------------- 5. cumsum along W: bf16 f -> fp32 S, channel-pair vectorized ----------------
// grid 640 (1 row/block), block 128 = channel pairs
__global__ __launch_bounds__(128) void cumsum_w(const __hip_bfloat16* __restrict__ f2,
                                                float* __restrict__ S) {
  int row = blockIdx.x;                            // 0..639
  int b = row / 160, y = row - (row / 160) * 160;
  int cp = threadIdx.x;                            // channel pair index
  const unsigned* src =
      (const unsigned*)((const short*)f2 + (((size_t)b * 162 + y + 1) * 162 + 1) * 256) + cp;
  float2* dst = (float2*)(S + (((size_t)b * 161 + y + 1) * 161) * 256) + cp;
  dst[0] = float2{0.f, 0.f};
  float r0 = 0.f, r1 = 0.f;
  for (int x4 = 0; x4 < 160; x4 += 4) {
    unsigned v[4];
#pragma unroll
    for (int k = 0; k < 4; k++) v[k] = src[(size_t)(x4 + k) * 128];
#pragma unroll
    for (int k = 0; k < 4; k++) {
      r0 += __uint_as_float((v[k] & 0xffffu) << 16);
      r1 += __uint_as_float(v[k] & 0xffff0000u);
      dst[(size_t)(x4 + k + 1) * 128] = float2{r0, r1};
    }
  }
}

// ---------------- 6. cumsum along H in place (16-deep load batching) ----------------
__global__ __launch_bounds__(256) void cumsum_h(float* __restrict__ S) {
  int bi = blockIdx.x;  // 4*161
  int b = bi / 161, q = bi - (bi / 161) * 161;
  int c = threadIdx.x;
  float* col = S + (((size_t)b * 161) * 161 + q) * 256 + c;
  const size_t ys = (size_t)161 * 256;
  col[0] = 0.f;
  float run = 0.f;
  for (int y0 = 1; y0 <= 160; y0 += 16) {
    float v[16];
#pragma unroll
    for (int k = 0; k < 16; k++) v[k] = col[(size_t)(y0 + k) * ys];
#pragma unroll
    for (int k = 0; k < 16; k++) { run += v[k]; col[(size_t)(y0 + k) * ys] = run; }
  }
}

// ---------------- 7. fused ROI 7x7 adaptive pool + MLP + mask + L2 normalize ----------------
// block 256 threads = 1 box: gather pooled[256] into LDS, then MLP on 128 lanes.
__global__ __launch_bounds__(256) void roi_mlp(const float* __restrict__ S,
                                               const float* __restrict__ bbox,
                                               const float* __restrict__ w1t,
                                               const float* __restrict__ b1,
                                               const float* __restrict__ w2t,
                                               const float* __restrict__ b2,
                                               float* __restrict__ out) {
  int bn = blockIdx.x;  // 0..2047
  int b = bn >> 9;
  int t = threadIdx.x;
  __shared__ float pl[256];
  __shared__ float hh[128];
  __shared__ float red[2];

  float bx1 = bbox[bn * 4 + 0], by1 = bbox[bn * 4 + 1];
  float bx2 = bbox[bn * 4 + 2], by2 = bbox[bn * 4 + 3];
  int x1 = min(max((int)floorf(bx1 * 160.f), 0), 160);
  int y1 = min(max((int)floorf(by1 * 160.f), 0), 160);
  int x2 = min(max((int)floorf(bx2 * 160.f), 0), 160);
  int y2 = min(max((int)floorf(by2 * 160.f), 0), 160);
  int vld = (x2 > x1 && y2 > y1) ? 1 : 0;
  int hl = max(y2 - y1, 1), wl = max(x2 - x1, 1);
  int hs[7], he[7], ws_[7], we_[7];
  float rh[7], rw[7];
#pragma unroll
  for (int i = 0; i < 7; i++) {
    hs[i] = y1 + (i * hl) / 7;
    he[i] = y1 + ((i + 1) * hl + 6) / 7;
    rh[i] = 1.f / (float)(he[i] - hs[i]);
    ws_[i] = x1 + (i * wl) / 7;
    we_[i] = x1 + ((i + 1) * wl + 6) / 7;
    rw[i] = 1.f / (float)(we_[i] - ws_[i]);
  }
  const float* Sb = S + (size_t)b * 161 * 161 * 256 + t;
  float acc = 0.f;
#pragma unroll
  for (int i = 0; i < 7; i++) {
    const float* rE = Sb + (size_t)he[i] * (161 * 256);
    const float* rS = Sb + (size_t)hs[i] * (161 * 256);
#pragma unroll
    for (int j = 0; j < 7; j++) {
      size_t qe = (size_t)we_[j] * 256, qs = (size_t)ws_[j] * 256;
      float s = rE[qe] - rS[qe] - rE[qs] + rS[qs];
      acc += s * (rh[i] * rw[j]);
    }
  }
  pl[t] = acc * (1.f / 49.f);
  __syncthreads();

  float a = 0.f;
  if (t < 128) {
    a = b1[t];
#pragma unroll 8
    for (int k = 0; k < 256; k++) a += w1t[k * 128 + t] * pl[k];
    hh[t] = fmaxf(a, 0.f);
  }
  __syncthreads();
  float f = 0.f;
  if (t < 128) {
    f = b2[t];
#pragma unroll 8
    for (int k = 0; k < 128; k++) f += w2t[k * 128 + t] * hh[k];
    if (!vld) f = 0.f;
    float ss = f * f;
#pragma unroll
    for (int off = 32; off > 0; off >>= 1) ss += __shfl_xor(ss, off);
    if ((t & 63) == 0) red[t >> 6] = ss;
  }
  __syncthreads();
  if (t < 128) {
    float nrm = fmaxf(sqrtf(red[0] + red[1]), 1e-12f);
    out[(size_t)bn * 128 + t] = f / nrm;
  }
}

// ---------------- launch ----------------
extern "C" void kernel_launch(void* const* d_in, const int* in_sizes, int n_in,
                              void* d_out, int out_size, void* d_ws, size_t ws_size,
                              hipStream_t stream) {
  const float* x = (const float*)d_in[0];
  const float* bboxes = (const float*)d_in[1];
  const float* conv_w = (const float*)d_in[2];
  const float* conv_b = (const float*)d_in[3];
  const float* bn_g = (const float*)d_in[4];
  const float* bn_b = (const float*)d_in[5];
  const float* bn_m = (const float*)d_in[6];
  const float* bn_v = (const float*)d_in[7];
  const float* w1 = (const float*)d_in[8];
  const float* b1 = (const float*)d_in[9];
  const float* w2 = (const float*)d_in[10];
  const float* b2 = (const float*)d_in[11];

  char* ws = (char*)d_ws;
  const size_t PADB = (size_t)4 * 162 * 162 * 256 * 2;   // 53,747,712 B
  const size_t WPKB = (size_t)2 * 9 * 256 * 256 * 2;     // 2,359,296 B
  const size_t SB = (size_t)4 * 161 * 161 * 256 * 4;     // 106,172,416 B

  __hip_bfloat16* xpad = (__hip_bfloat16*)(ws);
  __hip_bfloat16* f1 = (__hip_bfloat16*)(ws + PADB);
  __hip_bfloat16* wpk = (__hip_bfloat16*)(ws + 2 * PADB);
  float* abuf = (float*)(ws + 2 * PADB + WPKB);
  float* S = (float*)(ws + 2 * PADB + WPKB + 4096);
  float* w1t = (float*)(ws + 2 * PADB + WPKB + 4096 + SB);
  float* w2t = w1t + 32768;

  prep_all<<<9954, 256, 0, stream>>>(xpad, f1, conv_w, wpk, conv_b, bn_g, bn_b, bn_m,
                                     bn_v, abuf, w1, w2, w1t, w2t);
  nchw2nhwc<<<12800, dim3(32, 8), 0, stream>>>(x, xpad);

  conv_bn_relu<<<800, 256, 0, stream>>>(xpad, f1, wpk, abuf, abuf + 512);
  conv_bn_relu<<<800, 256, 0, stream>>>(f1, xpad, wpk + (size_t)9 * 256 * 256, abuf + 256, abuf + 768);

  cumsum_w<<<640, 128, 0, stream>>>(xpad, S);
  cumsum_h<<<644, 256, 0, stream>>>(S);
  roi_mlp<<<2048, 256, 0, stream>>>(S, bboxes, w1t, b1, w2t, b2, (float*)d_out);
}